// Round 3
// baseline (373.485 us; speedup 1.0000x reference)
//
#include <hip/hip_runtime.h>
#include <hip/hip_fp16.h>

#define NB 2048
#define NT 60
#define NDL 100
#define ND 512
#define NH 256
#define NG 768

#define L2E  1.44269504f
#define L2E2 2.88539008f

typedef const float* __restrict__ fpp;
typedef _Float16 half8 __attribute__((ext_vector_type(8)));
typedef float floatx4 __attribute__((ext_vector_type(4)));

__device__ __forceinline__ float fast_rcp(float x) {
  return __builtin_amdgcn_rcpf(x);
}
__device__ __forceinline__ float fast_exp2(float x) {
#if __has_builtin(__builtin_amdgcn_exp2f)
  return __builtin_amdgcn_exp2f(x);
#else
  return exp2f(x);
#endif
}
__device__ __forceinline__ float fsin(float x) {
#if __has_builtin(__builtin_amdgcn_sinf)
  return __builtin_amdgcn_sinf(x * 0.15915494309189535f);
#else
  return __sinf(x);
#endif
}
__device__ __forceinline__ float fcos(float x) {
#if __has_builtin(__builtin_amdgcn_cosf)
  return __builtin_amdgcn_cosf(x * 0.15915494309189535f);
#else
  return __cosf(x);
#endif
}

// ---------------------------------------------------------------------------
// fp32 tiled GEMM (fc layer only, K=100): C = A*B^T + bias
// ---------------------------------------------------------------------------
__global__ __launch_bounds__(256) void gemm_fc(
    fpp A, fpp Bm, fpp bias, float* __restrict__ C,
    int M, int N, int K, int lda, int ldb, int ldc)
{
  __shared__ float As[16][68];
  __shared__ float Bs[16][68];
  const int bm = blockIdx.x * 64, bn = blockIdx.y * 64;
  const int tid = threadIdx.x;
  const int tx = tid & 15, ty = tid >> 4;
  float acc[4][4] = {};
  for (int k0 = 0; k0 < K; k0 += 16) {
#pragma unroll
    for (int i = 0; i < 4; i++) {
      int e = tid + i * 256;
      int m = e >> 4, k = e & 15;
      As[k][m] = (k0 + k < K) ? A[(size_t)(bm + m) * lda + k0 + k] : 0.f;
      Bs[k][m] = (k0 + k < K) ? Bm[(size_t)(bn + m) * ldb + k0 + k] : 0.f;
    }
    __syncthreads();
#pragma unroll
    for (int kk = 0; kk < 16; kk++) {
      float4 av = *(const float4*)&As[kk][ty * 4];
      float4 bv = *(const float4*)&Bs[kk][tx * 4];
      float a_[4] = {av.x, av.y, av.z, av.w};
      float b_[4] = {bv.x, bv.y, bv.z, bv.w};
#pragma unroll
      for (int i = 0; i < 4; i++)
#pragma unroll
        for (int j = 0; j < 4; j++)
          acc[i][j] = fmaf(a_[i], b_[j], acc[i][j]);
    }
    __syncthreads();
  }
#pragma unroll
  for (int i = 0; i < 4; i++) {
    int m = bm + ty * 4 + i;
#pragma unroll
    for (int j = 0; j < 4; j++) {
      int n = bn + tx * 4 + j;
      C[(size_t)m * ldc + n] = acc[i][j] + bias[n];
    }
  }
}

// ---------------------------------------------------------------------------
// BN partial sums: 64 blocks x 32 rows, coalesced, atomicAdd into s1/s2[512].
// ---------------------------------------------------------------------------
__global__ __launch_bounds__(256) void bn_partial(
    const float* __restrict__ h0, float* __restrict__ s1g,
    float* __restrict__ s2g)
{
  const int r0 = blockIdx.x * 32;
  const int tid = threadIdx.x;
  float a1 = 0.f, a2 = 0.f, b1 = 0.f, b2 = 0.f;
  for (int r = 0; r < 32; r++) {
    float v = h0[(size_t)(r0 + r) * ND + tid];
    float w = h0[(size_t)(r0 + r) * ND + tid + 256];
    a1 += v; a2 += v * v;
    b1 += w; b2 += w * w;
  }
  atomicAdd(&s1g[tid], a1);
  atomicAdd(&s2g[tid], a2);
  atomicAdd(&s1g[tid + 256], b1);
  atomicAdd(&s2g[tid + 256], b2);
}

// bn (stats from s1/s2) + leaky relu, writing fp16
__global__ void bn_lrelu_h16(const float* __restrict__ h0,
                             fpp g, fpp b,
                             const float* __restrict__ s1g,
                             const float* __restrict__ s2g,
                             __half* __restrict__ h16g)
{
  int idx = blockIdx.x * 256 + threadIdx.x;
  int d = idx & (ND - 1);
  float mu = s1g[d] * (1.f / NB);
  float var = s2g[d] * (1.f / NB) - mu * mu;
  float sc = g[d] * rsqrtf(var + 1e-5f);
  float sh = b[d] - mu * sc;
  float v = h0[idx] * sc + sh;
  h16g[idx] = __float2half(v >= 0.f ? v : 0.2f * v);
}

// ---------------------------------------------------------------------------
// One-time weight conversions fp32 -> fp16 (+ zero-padded jW 16x512).
// Gate weights PRE-SCALED by log2e (r,z) / 2*log2e (n): GRU transcendentals
// become raw v_exp. w1 pre-scaled by 2*log2e (tanh).
// ---------------------------------------------------------------------------
__global__ void convert_w(fpp whf, fpp whb, fpp w1, fpp wif, fpp wib, fpp jw,
                          __half* __restrict__ o_whf, __half* __restrict__ o_whb,
                          __half* __restrict__ o_w1, __half* __restrict__ o_wif,
                          __half* __restrict__ o_wib, __half* __restrict__ o_jw)
{
  int idx = blockIdx.x * 256 + threadIdx.x;  // 0 .. 1318911
  if (idx < 196608) {
    float s = ((idx >> 16) == 2) ? L2E2 : L2E;      // [768][256], gate = idx>>16
    o_whf[idx] = __float2half(whf[idx] * s);
  } else if (idx < 393216) {
    int e = idx - 196608;
    float s = ((e >> 16) == 2) ? L2E2 : L2E;
    o_whb[e] = __float2half(whb[e] * s);
  } else if (idx < 524288) {
    int e = idx - 393216;
    o_w1[e] = __float2half(w1[e] * L2E2);
  } else if (idx < 917504) {
    int e = idx - 524288;
    float s = ((e >> 17) == 2) ? L2E2 : L2E;        // [768][512], gate = e>>17
    o_wif[e] = __float2half(wif[e] * s);
  } else if (idx < 1310720) {
    int e = idx - 917504;
    float s = ((e >> 17) == 2) ? L2E2 : L2E;
    o_wib[e] = __float2half(wib[e] * s);
  } else if (idx < 1318912) {
    int e = idx - 1310720;           // 16 x 512, rows >= 6 zero
    o_jw[e] = (e < 6 * ND) ? __float2half(jw[e]) : __float2half(0.f);
  }
}

// ---------------------------------------------------------------------------
// fp16 MFMA GEMM, BOTH xg projections in one launch (grid.z selects dir).
// bih scaled (log2e per gate) in the epilogue to match scaled weights.
// ---------------------------------------------------------------------------
__global__ __launch_bounds__(256) void gemm16_dual(
    const __half* __restrict__ A,
    const __half* __restrict__ B0, const __half* __restrict__ B1,
    fpp bias0, fpp bias1, float* __restrict__ C0, float* __restrict__ C1,
    int N, int K)
{
  const __half* __restrict__ Bm = blockIdx.z ? B1 : B0;
  fpp bias = blockIdx.z ? bias1 : bias0;
  float* __restrict__ C = blockIdx.z ? C1 : C0;

  __shared__ __half As[64 * 40];
  __shared__ __half Bs[64 * 40];
  const int bm = blockIdx.x * 64, bn = blockIdx.y * 64;
  const int tid = threadIdx.x;
  const int wave = tid >> 6, lane = tid & 63;
  const int lm = lane & 15, quad = lane >> 4;
  floatx4 acc[4];
#pragma unroll
  for (int nt = 0; nt < 4; nt++) acc[nt] = (floatx4){0.f, 0.f, 0.f, 0.f};

  const int row = tid >> 2, kc = tid & 3;
  for (int k0 = 0; k0 < K; k0 += 32) {
    __syncthreads();
    *(float4*)&As[row * 40 + kc * 8] =
      *(const float4*)&A[(size_t)(bm + row) * K + k0 + kc * 8];
    *(float4*)&Bs[row * 40 + kc * 8] =
      *(const float4*)&Bm[(size_t)(bn + row) * K + k0 + kc * 8];
    __syncthreads();
    half8 af = *(const half8*)&As[(wave * 16 + lm) * 40 + quad * 8];
#pragma unroll
    for (int nt = 0; nt < 4; nt++) {
      half8 bf = *(const half8*)&Bs[(nt * 16 + lm) * 40 + quad * 8];
      acc[nt] = __builtin_amdgcn_mfma_f32_16x16x32_f16(af, bf, acc[nt], 0, 0, 0);
    }
  }
#pragma unroll
  for (int nt = 0; nt < 4; nt++) {
    int n = bn + nt * 16 + lm;
    float bv = bias[n] * ((n < 2 * NH) ? L2E : L2E2);
#pragma unroll
    for (int r = 0; r < 4; r++) {
      int m = bm + wave * 16 + quad * 4 + r;
      C[(size_t)m * N + n] = acc[nt][r] + bv;
    }
  }
}

// ---------------------------------------------------------------------------
// PERSISTENT GRU. kb 0..5 Whh in registers, kb 6..7 in LDS (wave-private).
// x-terms and biases folded into the MFMA C-operand init (no gate adds).
// Phase-split per column-half: [c0 MFMA chain][gates c0][c1 chain][gates c1]
// with s_setprio around MFMA clusters -> sibling wave's gate VALU/trans can
// overlap this wave's MFMA chain. Gate math: 5 trans/output fused form
// h' = [t*(ez+h) + (h-ez)] / [(t+1)*(1+ez)], t=exp2(n-pre), ez=exp2(-z-pre).
// ---------------------------------------------------------------------------
#define GATES(C) do {                                                        \
    _Pragma("unroll")                                                        \
    for (int r = 0; r < 4; r++) {                                            \
      float er = fast_exp2(-acc[0][C][r]);                                   \
      float rg = fast_rcp(1.f + er);                                         \
      float ez = fast_exp2(-acc[1][C][r]);                                   \
      float tt = fast_exp2(fmaf(rg, acc[2][C][r], xn4[C][r]));               \
      float dd = tt + 1.f;                                                   \
      float num = fmaf(tt, ez + hp[C][r], hp[C][r] - ez);                    \
      float den = fmaf(dd, ez, dd);                                          \
      float hv = num * fast_rcp(den);                                        \
      hp[C][r] = hv;                                                         \
      hCur[(quad * 4 + r) * 264 + (n0 + C * 16 + lm)] = __float2half(hv);    \
    }                                                                        \
  } while (0)

#define CHAIN(C) do {                                                        \
    half8 t6[3], t7[3];                                                      \
    _Pragma("unroll")                                                        \
    for (int g = 0; g < 3; g++) {                                            \
      const __half* wp = &wts[wb + (g * 4 + C * 2) * 512];                   \
      t6[g] = *(const half8*)wp;                                             \
      t7[g] = *(const half8*)(wp + 512);                                     \
    }                                                                        \
    _Pragma("unroll")                                                        \
    for (int kb = 0; kb < 6; kb++)                                           \
      _Pragma("unroll")                                                      \
      for (int g = 0; g < 3; g++)                                            \
        acc[g][C] = __builtin_amdgcn_mfma_f32_16x16x32_f16(                  \
            a[kb], __builtin_bit_cast(half8, breg[g][C][kb]), acc[g][C],     \
            0, 0, 0);                                                        \
    _Pragma("unroll")                                                        \
    for (int g = 0; g < 3; g++)                                              \
      acc[g][C] = __builtin_amdgcn_mfma_f32_16x16x32_f16(                    \
          a[6], t6[g], acc[g][C], 0, 0, 0);                                  \
    _Pragma("unroll")                                                        \
    for (int g = 0; g < 3; g++)                                              \
      acc[g][C] = __builtin_amdgcn_mfma_f32_16x16x32_f16(                    \
          a[7], t7[g], acc[g][C], 0, 0, 0);                                  \
  } while (0)

__global__ __launch_bounds__(512, 2) void gru_persistent(
    const float* __restrict__ xg_f, const float* __restrict__ xg_b,
    const __half* __restrict__ whh16_f, const __half* __restrict__ whh16_b,
    fpp bhh_f, fpp bhh_b, __half* __restrict__ seq)
{
  const int dir  = blockIdx.x & 1;
  const int tile = blockIdx.x >> 1;
  const int bm   = tile * 16;
  const float* __restrict__ xg = dir ? xg_b : xg_f;
  const __half* __restrict__ Whh = dir ? whh16_b : whh16_f;
  fpp bhh = dir ? bhh_b : bhh_f;
  const int dcol = dir * NH;
  const int tid = threadIdx.x;
  const int wave = tid >> 6, lane = tid & 63;
  const int lm = lane & 15, quad = lane >> 4;
  const int n0 = wave * 32;

  __shared__ __half h16s[2][16 * 264];        // 16.9 KB
  __shared__ __half wts[96 * 512];            // 96 KB: kb=6,7 tails, per-wave

  floatx4 breg[3][2][6];
  {
    const __half* bp[3][2];
#pragma unroll
    for (int g = 0; g < 3; g++)
#pragma unroll
      for (int c = 0; c < 2; c++)
        bp[g][c] = Whh + (size_t)(g * NH + n0 + c * 16 + lm) * NH + quad * 8;

#pragma unroll
    for (int g = 0; g < 3; g++)
#pragma unroll
      for (int c = 0; c < 2; c++)
#pragma unroll
        for (int kb = 0; kb < 6; kb++)
          breg[g][c][kb] = *(const floatx4*)(bp[g][c] + kb * 32);
#pragma unroll
    for (int g = 0; g < 3; g++)
#pragma unroll
      for (int c = 0; c < 2; c++)
#pragma unroll
        for (int kb = 0; kb < 6; kb++)
          asm volatile("" : "+v"(breg[g][c][kb]));

    // one-time stage of kb=6,7 into LDS (lane-linear, conflict-free b128)
#pragma unroll
    for (int g = 0; g < 3; g++)
#pragma unroll
      for (int c = 0; c < 2; c++)
#pragma unroll
        for (int k2 = 0; k2 < 2; k2++)
          *(float4*)&wts[(wave * 12 + g * 4 + c * 2 + k2) * 512 + lane * 8] =
            *(const float4*)(bp[g][c] + 192 + k2 * 32);
  }

  floatx4 xr4[2], xz4[2], xn4[2];
  float bn_[2];
#pragma unroll
  for (int c = 0; c < 2; c++) {
    int n = n0 + c * 16 + lm;
    float br = bhh[n] * L2E, bz = bhh[NH + n] * L2E;
    bn_[c] = bhh[2 * NH + n] * L2E2;
#pragma unroll
    for (int r = 0; r < 4; r++) {
      int m = bm + quad * 4 + r;
      const float* xp = xg + (size_t)m * NG + n;
      xr4[c][r] = xp[0] + br;            // pre-biased (scaled domain)
      xz4[c][r] = xp[NH] + bz;
      xn4[c][r] = xp[2 * NH];
    }
  }

  float hp[2][4];
#pragma unroll
  for (int c = 0; c < 2; c++)
#pragma unroll
    for (int r = 0; r < 4; r++) hp[c][r] = 0.f;

  const int arow = lm * 264 + quad * 8;
  const int cm = tid >> 5, cpart = tid & 31;
  const int wb = wave * 6144 + lane * 8;      // LDS weight base (halves)

  __half* seqp = seq + ((size_t)(bm + cm) * NT + (dir ? NT - 1 : 0)) * ND
                 + dcol + cpart * 8;
  const ptrdiff_t seqd = dir ? -(ptrdiff_t)ND : (ptrdiff_t)ND;

  for (int step = 0; step < NT; step++) {
    const int cur = step & 1, prv = cur ^ 1;
    __half* __restrict__ hCur = h16s[cur];
    const __half* __restrict__ hPrv = h16s[prv];
    floatx4 acc[3][2];
#pragma unroll
    for (int c = 0; c < 2; c++) {
      acc[0][c] = xr4[c];
      acc[1][c] = xz4[c];
      acc[2][c] = (floatx4){bn_[c], bn_[c], bn_[c], bn_[c]};
    }

    if (step > 0) {
      {
        float4 v = *(const float4*)&hPrv[cm * 264 + cpart * 8];
        *(float4*)seqp = v;
        seqp += seqd;
      }
      half8 a[8];
#pragma unroll
      for (int kb = 0; kb < 8; kb++)
        a[kb] = *(const half8*)&hPrv[arow + kb * 32];

      __builtin_amdgcn_s_setprio(1);
      CHAIN(0);
      __builtin_amdgcn_s_setprio(0);
      GATES(0);
      __builtin_amdgcn_s_setprio(1);
      CHAIN(1);
      __builtin_amdgcn_s_setprio(0);
      GATES(1);
    } else {
      GATES(0);
      GATES(1);
    }
    __syncthreads();
  }

  {
    const __half* hLast = h16s[(NT - 1) & 1];
    float4 v = *(const float4*)&hLast[cm * 264 + cpart * 8];
    *(float4*)seqp = v;
  }
}

// ---------------------------------------------------------------------------
// Attention scores + gJ via MFMA, M=128/block, 2x2 wave partition, with
// register-prefetch pipeline: k0+1's global loads issue before k0's compute,
// hiding L2 latency under the MFMA phase.
// ---------------------------------------------------------------------------
__global__ __launch_bounds__(256) void attn_score_mfma(
    const __half* __restrict__ seq, const __half* __restrict__ w116,
    const __half* __restrict__ jw16, fpp b1, fpp W2,
    float* __restrict__ scores, float* __restrict__ gJ)
{
  const int bm = blockIdx.x * 128;
  const int tid = threadIdx.x;
  const int wave = tid >> 6, lane = tid & 63;
  const int lm = lane & 15, quad = lane >> 4;
  const int mh = wave & 1;       // rows mh*64 .. mh*64+63
  const int nh = wave >> 1;      // nt nh*8 .. nh*8+7

  __shared__ __half As[128 * 40];
  __shared__ __half Bs[256 * 40];
  __shared__ __half Js[16 * 40];
  __shared__ float partial[2][128];

  floatx4 acc[4][8];
  floatx4 accJ[4];
#pragma unroll
  for (int t = 0; t < 4; t++) {
#pragma unroll
    for (int u = 0; u < 8; u++) acc[t][u] = (floatx4){0.f, 0.f, 0.f, 0.f};
    accJ[t] = (floatx4){0.f, 0.f, 0.f, 0.f};
  }

  const int srow = tid >> 2, skc8 = (tid & 3) * 8;
  float4 pa[2], pb[4], pj = {};

#define LOADK(K0) do {                                                       \
    _Pragma("unroll")                                                        \
    for (int i = 0; i < 2; i++)                                              \
      pa[i] = *(const float4*)&seq[(size_t)(bm + srow + i * 64) * ND + (K0) + skc8]; \
    _Pragma("unroll")                                                        \
    for (int i = 0; i < 4; i++)                                              \
      pb[i] = *(const float4*)&w116[(size_t)(srow + i * 64) * ND + (K0) + skc8];     \
    if (tid < 64) pj = *(const float4*)&jw16[(size_t)srow * ND + (K0) + skc8];       \
  } while (0)

  LOADK(0);
  for (int k0 = 0; k0 < ND; k0 += 32) {
    __syncthreads();
#pragma unroll
    for (int i = 0; i < 2; i++)
      *(float4*)&As[(srow + i * 64) * 40 + skc8] = pa[i];
#pragma unroll
    for (int i = 0; i < 4; i++)
      *(float4*)&Bs[(srow + i * 64) * 40 + skc8] = pb[i];
    if (tid < 64) *(float4*)&Js[srow * 40 + skc8] = pj;
    if (k0 + 32 < ND) LOADK(k0 + 32);
    __syncthreads();

    half8 a[4];
#pragma unroll
    for (int t = 0; t < 4; t++)
      a[t] = *(const half8*)&As[((mh * 4 + t) * 16 + lm) * 40 + quad * 8];
#pragma unroll
    for (int u = 0; u < 8; u++) {
      half8 bf = *(const half8*)&Bs[((nh * 8 + u) * 16 + lm) * 40 + quad * 8];
#pragma unroll
      for (int t = 0; t < 4; t++)
        acc[t][u] = __builtin_amdgcn_mfma_f32_16x16x32_f16(a[t], bf, acc[t][u], 0, 0, 0);
    }
    if (nh == 1) {
      half8 bj = *(const half8*)&Js[lm * 40 + quad * 8];
#pragma unroll
      for (int t = 0; t < 4; t++)
        accJ[t] = __builtin_amdgcn_mfma_f32_16x16x32_f16(a[t], bj, accJ[t], 0, 0, 0);
    }
  }
#undef LOADK

  float rs[4][4] = {};
#pragma unroll
  for (int u = 0; u < 8; u++) {
    int n = (nh * 8 + u) * 16 + lm;
    float b1v = b1[n] * L2E2, w2v = W2[n];
#pragma unroll
    for (int t = 0; t < 4; t++)
#pragma unroll
      for (int r = 0; r < 4; r++) {
        float tt = fast_exp2(acc[t][u][r] + b1v);
        float th = fmaf(-2.f, fast_rcp(tt + 1.f), 1.f);   // tanh
        rs[t][r] = fmaf(th, w2v, rs[t][r]);
      }
  }
#pragma unroll
  for (int t = 0; t < 4; t++)
#pragma unroll
    for (int r = 0; r < 4; r++) {
      rs[t][r] += __shfl_xor(rs[t][r], 1);
      rs[t][r] += __shfl_xor(rs[t][r], 2);
      rs[t][r] += __shfl_xor(rs[t][r], 4);
      rs[t][r] += __shfl_xor(rs[t][r], 8);
    }
  if (lm == 0) {
#pragma unroll
    for (int t = 0; t < 4; t++)
#pragma unroll
      for (int r = 0; r < 4; r++)
        partial[nh][mh * 64 + t * 16 + quad * 4 + r] = rs[t][r];
  }
  if (nh == 1) {
#pragma unroll
    for (int t = 0; t < 4; t++)
#pragma unroll
      for (int r = 0; r < 4; r++) {
        int row = bm + mh * 64 + t * 16 + quad * 4 + r;
        gJ[(size_t)row * 16 + lm] = accJ[t][r];
      }
  }
  __syncthreads();
  if (tid < 128) scores[bm + tid] = partial[0][tid] + partial[1][tid];
}

// ---------------------------------------------------------------------------
// FUSED softmax + cJ + scalar FK. One wave per batch row b.
// FK trig via hardware v_sin/v_cos (args bounded to +-3.15 rad).
// ---------------------------------------------------------------------------
__constant__ float c_lower[6] = {-3.1416f, -1.5708f, -3.1416f, -2.6f, -1.5708f, -1.2f};
__constant__ float c_upper[6] = { 3.1416f,  1.5708f,  3.1416f,  0.1f,  1.5708f,  1.2f};

__global__ __launch_bounds__(64) void attn_post(
    const float* __restrict__ scores_in, const float* __restrict__ gJ,
    fpp jb, float* __restrict__ out)
{
  const int b = blockIdx.x;
  const int t = threadIdx.x;    // 64 lanes, lanes 0..59 active for FK

  // --- softmax over time (wave-wide) ---
  float v = (t < NT) ? scores_in[(size_t)b * NT + t] : -1e30f;
  float m = v;
#pragma unroll
  for (int off = 32; off >= 1; off >>= 1) m = fmaxf(m, __shfl_xor(m, off));
  float e = (t < NT) ? __expf(v - m) : 0.f;
  float sum = e;
#pragma unroll
  for (int off = 32; off >= 1; off >>= 1) sum += __shfl_xor(sum, off);
  float w = e * fast_rcp(sum);

  // --- stage gJ[b] (60x16) + weights into LDS ---
  __shared__ float gj[NT * 16];
  __shared__ float wl[64];
  __shared__ float cj[16];
  wl[t] = w;
  const float* gsrc = gJ + (size_t)b * NT * 16;
#pragma unroll
  for (int i = 0; i < 15; i++) gj[t + i * 64] = gsrc[t + i * 64];
  __syncthreads();

  // --- cJ[j] = sum_t w[t]*gJ[t][j] ---
  if (t < 16) {
    float s = 0.f;
    for (int tt = 0; tt < NT; tt++) s += wl[tt] * gj[tt * 16 + t];
    cj[t] = s;
  }
  __syncthreads();

  if (t >= NT) return;

  float th[6];
#pragma unroll
  for (int j = 0; j < 6; j++) {
    float jnt = gj[t * 16 + j] + cj[j] + jb[j];
    th[j] = jnt * (c_upper[j] - c_lower[j]) + c_lower[j];
  }

  float c0x = 1.f, c0y = 0.f, c0z = 0.f;
  float c1x = 0.f, c1y = 1.f, c1z = 0.f;
  float c2x = 0.f, c2y = 0.f, c2z = 1.f;
  float px = 0.f, py = 0.f, pz = 0.1f;
  float s, cc, tx_, ty_, tz_, ux_, uy_, uz_;

  // rotZ(th0)
  s = fsin(th[0]); cc = fcos(th[0]);
  tx_ = cc * c0x + s * c1x; ty_ = cc * c0y + s * c1y; tz_ = cc * c0z + s * c1z;
  ux_ = -s * c0x + cc * c1x; uy_ = -s * c0y + cc * c1y; uz_ = -s * c0z + cc * c1z;
  c0x = tx_; c0y = ty_; c0z = tz_; c1x = ux_; c1y = uy_; c1z = uz_;

  float shx = px, shy = py, shz = pz;  // shoulder2
  // rotX(th1)
  s = fsin(th[1]); cc = fcos(th[1]);
  tx_ = cc * c1x + s * c2x; ty_ = cc * c1y + s * c2y; tz_ = cc * c1z + s * c2z;
  ux_ = -s * c1x + cc * c2x; uy_ = -s * c1y + cc * c2y; uz_ = -s * c1z + cc * c2z;
  c1x = tx_; c1y = ty_; c1z = tz_; c2x = ux_; c2y = uy_; c2z = uz_;

  // rotY(th2)
  s = fsin(th[2]); cc = fcos(th[2]);
  tx_ = cc * c0x - s * c2x; ty_ = cc * c0y - s * c2y; tz_ = cc * c0z - s * c2z;
  ux_ = s * c0x + cc * c2x; uy_ = s * c0y + cc * c2y; uz_ = s * c0z + cc * c2z;
  c0x = tx_; c0y = ty_; c0z = tz_; c2x = ux_; c2y = uy_; c2z = uz_;

  // joint3 offset -> forearm
  px -= 0.25f * c1x; py -= 0.25f * c1y; pz -= 0.25f * c1z;
  float fox = px, foy = py, foz = pz;
  // rotX(th3)
  s = fsin(th[3]); cc = fcos(th[3]);
  tx_ = cc * c1x + s * c2x; ty_ = cc * c1y + s * c2y; tz_ = cc * c1z + s * c2z;
  ux_ = -s * c1x + cc * c2x; uy_ = -s * c1y + cc * c2y; uz_ = -s * c1z + cc * c2z;
  c1x = tx_; c1y = ty_; c1z = tz_; c2x = ux_; c2y = uy_; c2z = uz_;

  // rotY(th4)
  s = fsin(th[4]); cc = fcos(th[4]);
  tx_ = cc * c0x - s * c2x; ty_ = cc * c0y - s * c2y; tz_ = cc * c0z - s * c2z;
  ux_ = s * c0x + cc * c2x; uy_ = s * c0y + cc * c2y; uz_ = s * c0z + cc * c2z;
  c0x = tx_; c0y = ty_; c0z = tz_; c2x = ux_; c2y = uy_; c2z = uz_;

  // joint5 offset -> wrist
  px -= 0.25f * c1x; py -= 0.25f * c1y; pz -= 0.25f * c1z;
  float wx = px, wy = py, wz = pz;
  // rotX(th5)
  s = fsin(th[5]); cc = fcos(th[5]);
  tx_ = cc * c1x + s * c2x; ty_ = cc * c1y + s * c2y; tz_ = cc * c1z + s * c2z;
  ux_ = -s * c1x + cc * c2x; uy_ = -s * c1y + cc * c2y; uz_ = -s * c1z + cc * c2z;
  c1x = tx_; c1y = ty_; c1z = tz_; c2x = ux_; c2y = uy_; c2z = uz_;

  float f1x = wx - 0.08f * c1x + 0.02f * c2x;
  float f1y = wy - 0.08f * c1y + 0.02f * c2y;
  float f1z = wz - 0.08f * c1z + 0.02f * c2z;
  float f4x = wx - 0.08f * c1x - 0.02f * c2x;
  float f4y = wy - 0.08f * c1y - 0.02f * c2y;
  float f4z = wz - 0.08f * c1z - 0.02f * c2z;

  float dsx = shx - fox, dsy = shy - foy, dsz = shz - foz;
  float dwx = wx - fox, dwy = wy - foy, dwz = wz - foz;
  float bodyL = 0.5f * (sqrtf(dsx * dsx + dsy * dsy + dsz * dsz) +
                        sqrtf(dwx * dwx + dwy * dwy + dwz * dwz));
  float inv = fast_rcp(bodyL);

  float* o = out + ((size_t)b * NT + t) * 9;
  o[0] = (wx - shx) * inv; o[1] = (wy - shy) * inv; o[2] = (wz - shz) * inv;
  o[3] = (f1x - shx) * inv; o[4] = (f1y - shy) * inv; o[5] = (f1z - shz) * inv;
  o[6] = (f4x - shx) * inv; o[7] = (f4y - shy) * inv; o[8] = (f4z - shz) * inv;
}

// ---------------------------------------------------------------------------
extern "C" void kernel_launch(void* const* d_in, const int* in_sizes, int n_in,
                              void* d_out, int out_size, void* d_ws, size_t ws_size,
                              hipStream_t stream)
{
  fpp z     = (fpp)d_in[0];
  fpp W_fc  = (fpp)d_in[1];
  fpp b_fc  = (fpp)d_in[2];
  fpp bn_g  = (fpp)d_in[3];
  fpp bn_b  = (fpp)d_in[4];
  fpp Wih_f = (fpp)d_in[5];
  fpp Whh_f = (fpp)d_in[6];
  fpp bih_f = (fpp)d_in[7];
  fpp bhh_f = (fpp)d_in[8];
  fpp Wih_b = (fpp)d_in[9];
  fpp Whh_b = (fpp)d_in[10];
  fpp bih_b = (fpp)d_in[11];
  fpp bhh_b = (fpp)d_in[12];
  fpp aW1   = (fpp)d_in[13];
  fpp ab1   = (fpp)d_in[14];
  fpp aW2   = (fpp)d_in[15];
  fpp jW    = (fpp)d_in[16];
  fpp jb    = (fpp)d_in[17];

  float* ws     = (float*)d_ws;
  float* h0     = ws;                        // 2048*512 fp32
  float* xg_f   = h0 + 1048576;              // 2048*768 fp32
  float* xg_b   = xg_f + 1572864;            // 2048*768 fp32
  float* bns1   = xg_b + 1572864;            // 512
  float* bns2   = bns1 + 512;                // 512
  float* scores = bns2 + 512;                // 2048*60
  float* cbuf   = scores + 122880;           // 2048*512 (layout keep)
  __half* gseq    = (__half*)(cbuf + 1048576);   // 2048*60*512 fp16 (126 MB)
  __half* whh16_f = gseq + 62914560;             // 768*256
  __half* whh16_b = whh16_f + 196608;            // 768*256
  __half* w116    = whh16_b + 196608;            // 256*512
  __half* wih16_f = w116 + 131072;               // 768*512
  __half* wih16_b = wih16_f + 393216;            // 768*512
  __half* h16g    = wih16_b + 393216;            // 2048*512
  __half* jw16    = h16g + 1048576;              // 16*512
  float*  gJ      = (float*)(jw16 + 8192);       // 122880*16 fp32 (7.9 MB)

  // 0. weight conversions fp32->fp16 (pre-scaled log2 domain) + BN acc zero
  convert_w<<<5152, 256, 0, stream>>>(Whh_f, Whh_b, aW1, Wih_f, Wih_b, jW,
                                      whh16_f, whh16_b, w116, wih16_f, wih16_b,
                                      jw16);
  hipMemsetAsync(bns1, 0, 1024 * sizeof(float), stream);
  // 1. fc: h0 = z @ W_fc^T + b_fc (fp32, K=100)
  gemm_fc<<<dim3(32, 8), 256, 0, stream>>>(z, W_fc, b_fc, h0,
                                           NB, ND, NDL, NDL, NDL, ND);
  // 2. batchnorm (training stats, parallel partials) + leaky relu -> fp16 h
  bn_partial<<<64, 256, 0, stream>>>(h0, bns1, bns2);
  bn_lrelu_h16<<<4096, 256, 0, stream>>>(h0, bn_g, bn_b, bns1, bns2, h16g);
  // 3. BOTH time-invariant input projections in one launch
  gemm16_dual<<<dim3(32, 12, 2), 256, 0, stream>>>(
      h16g, wih16_f, wih16_b, bih_f, bih_b, xg_f, xg_b, NG, ND);
  // 4. ENTIRE GRU recurrence: one persistent launch, 8 waves/block
  gru_persistent<<<256, 512, 0, stream>>>(xg_f, xg_b, whh16_f, whh16_b,
                                          bhh_f, bhh_b, gseq);
  // 5. attention scores + gJ (2x2 wave-partitioned MFMA, reg-prefetch)
  attn_score_mfma<<<960, 256, 0, stream>>>(gseq, w116, jw16, ab1, aW2,
                                           scores, gJ);
  // 6. fused softmax + cJ + FK
  attn_post<<<NB, 64, 0, stream>>>(scores, gJ, jb, (float*)d_out);
}

// Round 4
// 282.412 us; speedup vs baseline: 1.3225x; 1.3225x over previous
//
#include <hip/hip_runtime.h>
#include <hip/hip_fp16.h>

#define NB 2048
#define NT 60
#define NDL 100
#define ND 512
#define NH 256
#define NG 768

#define L2E  1.44269504f
#define L2E2 2.88539008f

typedef const float* __restrict__ fpp;
typedef _Float16 half8 __attribute__((ext_vector_type(8)));
typedef float floatx4 __attribute__((ext_vector_type(4)));

__device__ __forceinline__ float fast_rcp(float x) {
  return __builtin_amdgcn_rcpf(x);
}
__device__ __forceinline__ float fast_exp2(float x) {
#if __has_builtin(__builtin_amdgcn_exp2f)
  return __builtin_amdgcn_exp2f(x);
#else
  return exp2f(x);
#endif
}
__device__ __forceinline__ float fsin(float x) {
#if __has_builtin(__builtin_amdgcn_sinf)
  return __builtin_amdgcn_sinf(x * 0.15915494309189535f);
#else
  return __sinf(x);
#endif
}
__device__ __forceinline__ float fcos(float x) {
#if __has_builtin(__builtin_amdgcn_cosf)
  return __builtin_amdgcn_cosf(x * 0.15915494309189535f);
#else
  return __cosf(x);
#endif
}

// ---------------------------------------------------------------------------
// fp32 tiled GEMM (fc layer only, K=100): C = A*B^T + bias
// ---------------------------------------------------------------------------
__global__ __launch_bounds__(256) void gemm_fc(
    fpp A, fpp Bm, fpp bias, float* __restrict__ C,
    int M, int N, int K, int lda, int ldb, int ldc)
{
  __shared__ float As[16][68];
  __shared__ float Bs[16][68];
  const int bm = blockIdx.x * 64, bn = blockIdx.y * 64;
  const int tid = threadIdx.x;
  const int tx = tid & 15, ty = tid >> 4;
  float acc[4][4] = {};
  for (int k0 = 0; k0 < K; k0 += 16) {
#pragma unroll
    for (int i = 0; i < 4; i++) {
      int e = tid + i * 256;
      int m = e >> 4, k = e & 15;
      As[k][m] = (k0 + k < K) ? A[(size_t)(bm + m) * lda + k0 + k] : 0.f;
      Bs[k][m] = (k0 + k < K) ? Bm[(size_t)(bn + m) * ldb + k0 + k] : 0.f;
    }
    __syncthreads();
#pragma unroll
    for (int kk = 0; kk < 16; kk++) {
      float4 av = *(const float4*)&As[kk][ty * 4];
      float4 bv = *(const float4*)&Bs[kk][tx * 4];
      float a_[4] = {av.x, av.y, av.z, av.w};
      float b_[4] = {bv.x, bv.y, bv.z, bv.w};
#pragma unroll
      for (int i = 0; i < 4; i++)
#pragma unroll
        for (int j = 0; j < 4; j++)
          acc[i][j] = fmaf(a_[i], b_[j], acc[i][j]);
    }
    __syncthreads();
  }
#pragma unroll
  for (int i = 0; i < 4; i++) {
    int m = bm + ty * 4 + i;
#pragma unroll
    for (int j = 0; j < 4; j++) {
      int n = bn + tx * 4 + j;
      C[(size_t)m * ldc + n] = acc[i][j] + bias[n];
    }
  }
}

// ---------------------------------------------------------------------------
// BN partial sums: 64 blocks x 32 rows, coalesced, atomicAdd into s1/s2[512].
// ---------------------------------------------------------------------------
__global__ __launch_bounds__(256) void bn_partial(
    const float* __restrict__ h0, float* __restrict__ s1g,
    float* __restrict__ s2g)
{
  const int r0 = blockIdx.x * 32;
  const int tid = threadIdx.x;
  float a1 = 0.f, a2 = 0.f, b1 = 0.f, b2 = 0.f;
  for (int r = 0; r < 32; r++) {
    float v = h0[(size_t)(r0 + r) * ND + tid];
    float w = h0[(size_t)(r0 + r) * ND + tid + 256];
    a1 += v; a2 += v * v;
    b1 += w; b2 += w * w;
  }
  atomicAdd(&s1g[tid], a1);
  atomicAdd(&s2g[tid], a2);
  atomicAdd(&s1g[tid + 256], b1);
  atomicAdd(&s2g[tid + 256], b2);
}

// bn (stats from s1/s2) + leaky relu, writing fp16
__global__ void bn_lrelu_h16(const float* __restrict__ h0,
                             fpp g, fpp b,
                             const float* __restrict__ s1g,
                             const float* __restrict__ s2g,
                             __half* __restrict__ h16g)
{
  int idx = blockIdx.x * 256 + threadIdx.x;
  int d = idx & (ND - 1);
  float mu = s1g[d] * (1.f / NB);
  float var = s2g[d] * (1.f / NB) - mu * mu;
  float sc = g[d] * rsqrtf(var + 1e-5f);
  float sh = b[d] - mu * sc;
  float v = h0[idx] * sc + sh;
  h16g[idx] = __float2half(v >= 0.f ? v : 0.2f * v);
}

// ---------------------------------------------------------------------------
// One-time weight conversions fp32 -> fp16 (+ zero-padded jW 16x512).
// Gate weights PRE-SCALED by log2e (r,z) / 2*log2e (n): GRU transcendentals
// become raw v_exp. w1 pre-scaled by 2*log2e (tanh).
// ---------------------------------------------------------------------------
__global__ void convert_w(fpp whf, fpp whb, fpp w1, fpp wif, fpp wib, fpp jw,
                          __half* __restrict__ o_whf, __half* __restrict__ o_whb,
                          __half* __restrict__ o_w1, __half* __restrict__ o_wif,
                          __half* __restrict__ o_wib, __half* __restrict__ o_jw)
{
  int idx = blockIdx.x * 256 + threadIdx.x;  // 0 .. 1318911
  if (idx < 196608) {
    float s = ((idx >> 16) == 2) ? L2E2 : L2E;      // [768][256], gate = idx>>16
    o_whf[idx] = __float2half(whf[idx] * s);
  } else if (idx < 393216) {
    int e = idx - 196608;
    float s = ((e >> 16) == 2) ? L2E2 : L2E;
    o_whb[e] = __float2half(whb[e] * s);
  } else if (idx < 524288) {
    int e = idx - 393216;
    o_w1[e] = __float2half(w1[e] * L2E2);
  } else if (idx < 917504) {
    int e = idx - 524288;
    float s = ((e >> 17) == 2) ? L2E2 : L2E;        // [768][512], gate = e>>17
    o_wif[e] = __float2half(wif[e] * s);
  } else if (idx < 1310720) {
    int e = idx - 917504;
    float s = ((e >> 17) == 2) ? L2E2 : L2E;
    o_wib[e] = __float2half(wib[e] * s);
  } else if (idx < 1318912) {
    int e = idx - 1310720;           // 16 x 512, rows >= 6 zero
    o_jw[e] = (e < 6 * ND) ? __float2half(jw[e]) : __float2half(0.f);
  }
}

// ---------------------------------------------------------------------------
// fp16 MFMA GEMM, BOTH xg projections in one launch (grid.z selects dir).
// bih scaled (log2e per gate) in the epilogue to match scaled weights.
// ---------------------------------------------------------------------------
__global__ __launch_bounds__(256) void gemm16_dual(
    const __half* __restrict__ A,
    const __half* __restrict__ B0, const __half* __restrict__ B1,
    fpp bias0, fpp bias1, float* __restrict__ C0, float* __restrict__ C1,
    int N, int K)
{
  const __half* __restrict__ Bm = blockIdx.z ? B1 : B0;
  fpp bias = blockIdx.z ? bias1 : bias0;
  float* __restrict__ C = blockIdx.z ? C1 : C0;

  __shared__ __half As[64 * 40];
  __shared__ __half Bs[64 * 40];
  const int bm = blockIdx.x * 64, bn = blockIdx.y * 64;
  const int tid = threadIdx.x;
  const int wave = tid >> 6, lane = tid & 63;
  const int lm = lane & 15, quad = lane >> 4;
  floatx4 acc[4];
#pragma unroll
  for (int nt = 0; nt < 4; nt++) acc[nt] = (floatx4){0.f, 0.f, 0.f, 0.f};

  const int row = tid >> 2, kc = tid & 3;
  for (int k0 = 0; k0 < K; k0 += 32) {
    __syncthreads();
    *(float4*)&As[row * 40 + kc * 8] =
      *(const float4*)&A[(size_t)(bm + row) * K + k0 + kc * 8];
    *(float4*)&Bs[row * 40 + kc * 8] =
      *(const float4*)&Bm[(size_t)(bn + row) * K + k0 + kc * 8];
    __syncthreads();
    half8 af = *(const half8*)&As[(wave * 16 + lm) * 40 + quad * 8];
#pragma unroll
    for (int nt = 0; nt < 4; nt++) {
      half8 bf = *(const half8*)&Bs[(nt * 16 + lm) * 40 + quad * 8];
      acc[nt] = __builtin_amdgcn_mfma_f32_16x16x32_f16(af, bf, acc[nt], 0, 0, 0);
    }
  }
#pragma unroll
  for (int nt = 0; nt < 4; nt++) {
    int n = bn + nt * 16 + lm;
    float bv = bias[n] * ((n < 2 * NH) ? L2E : L2E2);
#pragma unroll
    for (int r = 0; r < 4; r++) {
      int m = bm + wave * 16 + quad * 4 + r;
      C[(size_t)m * N + n] = acc[nt][r] + bv;
    }
  }
}

// ---------------------------------------------------------------------------
// PERSISTENT GRU. kb 0..5 Whh in registers, kb 6..7 in LDS (wave-private).
// x-terms and biases folded into the MFMA C-operand init (no gate adds).
// Phase-split per column-half with s_setprio around MFMA clusters.
// Gate math: 5 trans/output fused form
// h' = [t*(ez+h) + (h-ez)] / [(t+1)*(1+ez)], t=exp2(n-pre), ez=exp2(-z-pre).
// ---------------------------------------------------------------------------
#define GATES(C) do {                                                        \
    _Pragma("unroll")                                                        \
    for (int r = 0; r < 4; r++) {                                            \
      float er = fast_exp2(-acc[0][C][r]);                                   \
      float rg = fast_rcp(1.f + er);                                         \
      float ez = fast_exp2(-acc[1][C][r]);                                   \
      float tt = fast_exp2(fmaf(rg, acc[2][C][r], xn4[C][r]));               \
      float dd = tt + 1.f;                                                   \
      float num = fmaf(tt, ez + hp[C][r], hp[C][r] - ez);                    \
      float den = fmaf(dd, ez, dd);                                          \
      float hv = num * fast_rcp(den);                                        \
      hp[C][r] = hv;                                                         \
      hCur[(quad * 4 + r) * 264 + (n0 + C * 16 + lm)] = __float2half(hv);    \
    }                                                                        \
  } while (0)

#define CHAIN(C) do {                                                        \
    half8 t6[3], t7[3];                                                      \
    _Pragma("unroll")                                                        \
    for (int g = 0; g < 3; g++) {                                            \
      const __half* wp = &wts[wb + (g * 4 + C * 2) * 512];                   \
      t6[g] = *(const half8*)wp;                                             \
      t7[g] = *(const half8*)(wp + 512);                                     \
    }                                                                        \
    _Pragma("unroll")                                                        \
    for (int kb = 0; kb < 6; kb++)                                           \
      _Pragma("unroll")                                                      \
      for (int g = 0; g < 3; g++)                                            \
        acc[g][C] = __builtin_amdgcn_mfma_f32_16x16x32_f16(                  \
            a[kb], __builtin_bit_cast(half8, breg[g][C][kb]), acc[g][C],     \
            0, 0, 0);                                                        \
    _Pragma("unroll")                                                        \
    for (int g = 0; g < 3; g++)                                              \
      acc[g][C] = __builtin_amdgcn_mfma_f32_16x16x32_f16(                    \
          a[6], t6[g], acc[g][C], 0, 0, 0);                                  \
    _Pragma("unroll")                                                        \
    for (int g = 0; g < 3; g++)                                              \
      acc[g][C] = __builtin_amdgcn_mfma_f32_16x16x32_f16(                    \
          a[7], t7[g], acc[g][C], 0, 0, 0);                                  \
  } while (0)

__global__ __launch_bounds__(512, 2) void gru_persistent(
    const float* __restrict__ xg_f, const float* __restrict__ xg_b,
    const __half* __restrict__ whh16_f, const __half* __restrict__ whh16_b,
    fpp bhh_f, fpp bhh_b, __half* __restrict__ seq)
{
  const int dir  = blockIdx.x & 1;
  const int tile = blockIdx.x >> 1;
  const int bm   = tile * 16;
  const float* __restrict__ xg = dir ? xg_b : xg_f;
  const __half* __restrict__ Whh = dir ? whh16_b : whh16_f;
  fpp bhh = dir ? bhh_b : bhh_f;
  const int dcol = dir * NH;
  const int tid = threadIdx.x;
  const int wave = tid >> 6, lane = tid & 63;
  const int lm = lane & 15, quad = lane >> 4;
  const int n0 = wave * 32;

  __shared__ __half h16s[2][16 * 264];        // 16.9 KB
  __shared__ __half wts[96 * 512];            // 96 KB: kb=6,7 tails, per-wave

  floatx4 breg[3][2][6];
  {
    const __half* bp[3][2];
#pragma unroll
    for (int g = 0; g < 3; g++)
#pragma unroll
      for (int c = 0; c < 2; c++)
        bp[g][c] = Whh + (size_t)(g * NH + n0 + c * 16 + lm) * NH + quad * 8;

#pragma unroll
    for (int g = 0; g < 3; g++)
#pragma unroll
      for (int c = 0; c < 2; c++)
#pragma unroll
        for (int kb = 0; kb < 6; kb++)
          breg[g][c][kb] = *(const floatx4*)(bp[g][c] + kb * 32);
#pragma unroll
    for (int g = 0; g < 3; g++)
#pragma unroll
      for (int c = 0; c < 2; c++)
#pragma unroll
        for (int kb = 0; kb < 6; kb++)
          asm volatile("" : "+v"(breg[g][c][kb]));

    // one-time stage of kb=6,7 into LDS (lane-linear, conflict-free b128)
#pragma unroll
    for (int g = 0; g < 3; g++)
#pragma unroll
      for (int c = 0; c < 2; c++)
#pragma unroll
        for (int k2 = 0; k2 < 2; k2++)
          *(float4*)&wts[(wave * 12 + g * 4 + c * 2 + k2) * 512 + lane * 8] =
            *(const float4*)(bp[g][c] + 192 + k2 * 32);
  }

  floatx4 xr4[2], xz4[2], xn4[2];
  float bn_[2];
#pragma unroll
  for (int c = 0; c < 2; c++) {
    int n = n0 + c * 16 + lm;
    float br = bhh[n] * L2E, bz = bhh[NH + n] * L2E;
    bn_[c] = bhh[2 * NH + n] * L2E2;
#pragma unroll
    for (int r = 0; r < 4; r++) {
      int m = bm + quad * 4 + r;
      const float* xp = xg + (size_t)m * NG + n;
      xr4[c][r] = xp[0] + br;            // pre-biased (scaled domain)
      xz4[c][r] = xp[NH] + bz;
      xn4[c][r] = xp[2 * NH];
    }
  }

  float hp[2][4];
#pragma unroll
  for (int c = 0; c < 2; c++)
#pragma unroll
    for (int r = 0; r < 4; r++) hp[c][r] = 0.f;

  const int arow = lm * 264 + quad * 8;
  const int cm = tid >> 5, cpart = tid & 31;
  const int wb = wave * 6144 + lane * 8;      // LDS weight base (halves)

  __half* seqp = seq + ((size_t)(bm + cm) * NT + (dir ? NT - 1 : 0)) * ND
                 + dcol + cpart * 8;
  const ptrdiff_t seqd = dir ? -(ptrdiff_t)ND : (ptrdiff_t)ND;

  for (int step = 0; step < NT; step++) {
    const int cur = step & 1, prv = cur ^ 1;
    __half* __restrict__ hCur = h16s[cur];
    const __half* __restrict__ hPrv = h16s[prv];
    floatx4 acc[3][2];
#pragma unroll
    for (int c = 0; c < 2; c++) {
      acc[0][c] = xr4[c];
      acc[1][c] = xz4[c];
      acc[2][c] = (floatx4){bn_[c], bn_[c], bn_[c], bn_[c]};
    }

    if (step > 0) {
      {
        float4 v = *(const float4*)&hPrv[cm * 264 + cpart * 8];
        *(float4*)seqp = v;
        seqp += seqd;
      }
      half8 a[8];
#pragma unroll
      for (int kb = 0; kb < 8; kb++)
        a[kb] = *(const half8*)&hPrv[arow + kb * 32];

      __builtin_amdgcn_s_setprio(1);
      CHAIN(0);
      __builtin_amdgcn_s_setprio(0);
      GATES(0);
      __builtin_amdgcn_s_setprio(1);
      CHAIN(1);
      __builtin_amdgcn_s_setprio(0);
      GATES(1);
    } else {
      GATES(0);
      GATES(1);
    }
    __syncthreads();
  }

  {
    const __half* hLast = h16s[(NT - 1) & 1];
    float4 v = *(const float4*)&hLast[cm * 264 + cpart * 8];
    *(float4*)seqp = v;
  }
}

// ---------------------------------------------------------------------------
// Attention scores + gJ via MFMA. 512 thr / 8 waves, 2x4 wave partition:
// wave = (mh, nh) with mh = m-half (64 rows), nh = n-quarter (4 nt frags).
// Per-wave acc = 4x4 fragments (64 VGPRs) -> ~120 VGPR total -> 4 waves/SIMD
// (vs r15's 2x2 partition: 144 acc VGPRs, 2 waves/SIMD, latency-bound).
// Simple staging (known-good R2 form, no cross-barrier register prefetch).
// nh==3 waves additionally carry the gJ tile. Scores reduced via 4 partials.
// ---------------------------------------------------------------------------
__global__ __launch_bounds__(512, 4) void attn_score_mfma(
    const __half* __restrict__ seq, const __half* __restrict__ w116,
    const __half* __restrict__ jw16, fpp b1, fpp W2,
    float* __restrict__ scores, float* __restrict__ gJ)
{
  const int bm = blockIdx.x * 128;
  const int tid = threadIdx.x;
  const int wave = tid >> 6, lane = tid & 63;
  const int lm = lane & 15, quad = lane >> 4;
  const int mh = wave & 1;       // rows mh*64 .. mh*64+63
  const int nh = wave >> 1;      // nt frags nh*4 .. nh*4+3

  __shared__ __half As[128 * 40];
  __shared__ __half Bs[256 * 40];
  __shared__ __half Js[16 * 40];
  __shared__ float partial[4][128];

  floatx4 acc[4][4];
  floatx4 accJ[4];
#pragma unroll
  for (int t = 0; t < 4; t++) {
#pragma unroll
    for (int u = 0; u < 4; u++) acc[t][u] = (floatx4){0.f, 0.f, 0.f, 0.f};
    accJ[t] = (floatx4){0.f, 0.f, 0.f, 0.f};
  }

  const int srow = tid >> 2, skc8 = (tid & 3) * 8;

  for (int k0 = 0; k0 < ND; k0 += 32) {
    __syncthreads();
    *(float4*)&As[srow * 40 + skc8] =
      *(const float4*)&seq[(size_t)(bm + srow) * ND + k0 + skc8];
#pragma unroll
    for (int i = 0; i < 2; i++)
      *(float4*)&Bs[(srow + i * 128) * 40 + skc8] =
        *(const float4*)&w116[(size_t)(srow + i * 128) * ND + k0 + skc8];
    if (tid < 64)
      *(float4*)&Js[srow * 40 + skc8] =
        *(const float4*)&jw16[(size_t)srow * ND + k0 + skc8];
    __syncthreads();

    half8 a[4];
#pragma unroll
    for (int t = 0; t < 4; t++)
      a[t] = *(const half8*)&As[((mh * 4 + t) * 16 + lm) * 40 + quad * 8];
#pragma unroll
    for (int u = 0; u < 4; u++) {
      half8 bf = *(const half8*)&Bs[((nh * 4 + u) * 16 + lm) * 40 + quad * 8];
#pragma unroll
      for (int t = 0; t < 4; t++)
        acc[t][u] = __builtin_amdgcn_mfma_f32_16x16x32_f16(a[t], bf, acc[t][u], 0, 0, 0);
    }
    if (nh == 3) {
      half8 bj = *(const half8*)&Js[lm * 40 + quad * 8];
#pragma unroll
      for (int t = 0; t < 4; t++)
        accJ[t] = __builtin_amdgcn_mfma_f32_16x16x32_f16(a[t], bj, accJ[t], 0, 0, 0);
    }
  }

  float rs[4][4] = {};
#pragma unroll
  for (int u = 0; u < 4; u++) {
    int n = (nh * 4 + u) * 16 + lm;
    float b1v = b1[n] * L2E2, w2v = W2[n];
#pragma unroll
    for (int t = 0; t < 4; t++)
#pragma unroll
      for (int r = 0; r < 4; r++) {
        float tt = fast_exp2(acc[t][u][r] + b1v);
        float th = fmaf(-2.f, fast_rcp(tt + 1.f), 1.f);   // tanh
        rs[t][r] = fmaf(th, w2v, rs[t][r]);
      }
  }
#pragma unroll
  for (int t = 0; t < 4; t++)
#pragma unroll
    for (int r = 0; r < 4; r++) {
      rs[t][r] += __shfl_xor(rs[t][r], 1);
      rs[t][r] += __shfl_xor(rs[t][r], 2);
      rs[t][r] += __shfl_xor(rs[t][r], 4);
      rs[t][r] += __shfl_xor(rs[t][r], 8);
    }
  if (lm == 0) {
#pragma unroll
    for (int t = 0; t < 4; t++)
#pragma unroll
      for (int r = 0; r < 4; r++)
        partial[nh][mh * 64 + t * 16 + quad * 4 + r] = rs[t][r];
  }
  if (nh == 3) {
#pragma unroll
    for (int t = 0; t < 4; t++)
#pragma unroll
      for (int r = 0; r < 4; r++) {
        int row = bm + mh * 64 + t * 16 + quad * 4 + r;
        gJ[(size_t)row * 16 + lm] = accJ[t][r];
      }
  }
  __syncthreads();
  if (tid < 128)
    scores[bm + tid] = partial[0][tid] + partial[1][tid] +
                       partial[2][tid] + partial[3][tid];
}

// ---------------------------------------------------------------------------
// FUSED softmax + cJ + scalar FK. One wave per batch row b.
// FK trig via hardware v_sin/v_cos (args bounded to +-3.15 rad).
// ---------------------------------------------------------------------------
__constant__ float c_lower[6] = {-3.1416f, -1.5708f, -3.1416f, -2.6f, -1.5708f, -1.2f};
__constant__ float c_upper[6] = { 3.1416f,  1.5708f,  3.1416f,  0.1f,  1.5708f,  1.2f};

__global__ __launch_bounds__(64) void attn_post(
    const float* __restrict__ scores_in, const float* __restrict__ gJ,
    fpp jb, float* __restrict__ out)
{
  const int b = blockIdx.x;
  const int t = threadIdx.x;    // 64 lanes, lanes 0..59 active for FK

  // --- softmax over time (wave-wide) ---
  float v = (t < NT) ? scores_in[(size_t)b * NT + t] : -1e30f;
  float m = v;
#pragma unroll
  for (int off = 32; off >= 1; off >>= 1) m = fmaxf(m, __shfl_xor(m, off));
  float e = (t < NT) ? __expf(v - m) : 0.f;
  float sum = e;
#pragma unroll
  for (int off = 32; off >= 1; off >>= 1) sum += __shfl_xor(sum, off);
  float w = e * fast_rcp(sum);

  // --- stage gJ[b] (60x16) + weights into LDS ---
  __shared__ float gj[NT * 16];
  __shared__ float wl[64];
  __shared__ float cj[16];
  wl[t] = w;
  const float* gsrc = gJ + (size_t)b * NT * 16;
#pragma unroll
  for (int i = 0; i < 15; i++) gj[t + i * 64] = gsrc[t + i * 64];
  __syncthreads();

  // --- cJ[j] = sum_t w[t]*gJ[t][j] ---
  if (t < 16) {
    float s = 0.f;
    for (int tt = 0; tt < NT; tt++) s += wl[tt] * gj[tt * 16 + t];
    cj[t] = s;
  }
  __syncthreads();

  if (t >= NT) return;

  float th[6];
#pragma unroll
  for (int j = 0; j < 6; j++) {
    float jnt = gj[t * 16 + j] + cj[j] + jb[j];
    th[j] = jnt * (c_upper[j] - c_lower[j]) + c_lower[j];
  }

  float c0x = 1.f, c0y = 0.f, c0z = 0.f;
  float c1x = 0.f, c1y = 1.f, c1z = 0.f;
  float c2x = 0.f, c2y = 0.f, c2z = 1.f;
  float px = 0.f, py = 0.f, pz = 0.1f;
  float s, cc, tx_, ty_, tz_, ux_, uy_, uz_;

  // rotZ(th0)
  s = fsin(th[0]); cc = fcos(th[0]);
  tx_ = cc * c0x + s * c1x; ty_ = cc * c0y + s * c1y; tz_ = cc * c0z + s * c1z;
  ux_ = -s * c0x + cc * c1x; uy_ = -s * c0y + cc * c1y; uz_ = -s * c0z + cc * c1z;
  c0x = tx_; c0y = ty_; c0z = tz_; c1x = ux_; c1y = uy_; c1z = uz_;

  float shx = px, shy = py, shz = pz;  // shoulder2
  // rotX(th1)
  s = fsin(th[1]); cc = fcos(th[1]);
  tx_ = cc * c1x + s * c2x; ty_ = cc * c1y + s * c2y; tz_ = cc * c1z + s * c2z;
  ux_ = -s * c1x + cc * c2x; uy_ = -s * c1y + cc * c2y; uz_ = -s * c1z + cc * c2z;
  c1x = tx_; c1y = ty_; c1z = tz_; c2x = ux_; c2y = uy_; c2z = uz_;

  // rotY(th2)
  s = fsin(th[2]); cc = fcos(th[2]);
  tx_ = cc * c0x - s * c2x; ty_ = cc * c0y - s * c2y; tz_ = cc * c0z - s * c2z;
  ux_ = s * c0x + cc * c2x; uy_ = s * c0y + cc * c2y; uz_ = s * c0z + cc * c2z;
  c0x = tx_; c0y = ty_; c0z = tz_; c2x = ux_; c2y = uy_; c2z = uz_;

  // joint3 offset -> forearm
  px -= 0.25f * c1x; py -= 0.25f * c1y; pz -= 0.25f * c1z;
  float fox = px, foy = py, foz = pz;
  // rotX(th3)
  s = fsin(th[3]); cc = fcos(th[3]);
  tx_ = cc * c1x + s * c2x; ty_ = cc * c1y + s * c2y; tz_ = cc * c1z + s * c2z;
  ux_ = -s * c1x + cc * c2x; uy_ = -s * c1y + cc * c2y; uz_ = -s * c1z + cc * c2z;
  c1x = tx_; c1y = ty_; c1z = tz_; c2x = ux_; c2y = uy_; c2z = uz_;

  // rotY(th4)
  s = fsin(th[4]); cc = fcos(th[4]);
  tx_ = cc * c0x - s * c2x; ty_ = cc * c0y - s * c2y; tz_ = cc * c0z - s * c2z;
  ux_ = s * c0x + cc * c2x; uy_ = s * c0y + cc * c2y; uz_ = s * c0z + cc * c2z;
  c0x = tx_; c0y = ty_; c0z = tz_; c2x = ux_; c2y = uy_; c2z = uz_;

  // joint5 offset -> wrist
  px -= 0.25f * c1x; py -= 0.25f * c1y; pz -= 0.25f * c1z;
  float wx = px, wy = py, wz = pz;
  // rotX(th5)
  s = fsin(th[5]); cc = fcos(th[5]);
  tx_ = cc * c1x + s * c2x; ty_ = cc * c1y + s * c2y; tz_ = cc * c1z + s * c2z;
  ux_ = -s * c1x + cc * c2x; uy_ = -s * c1y + cc * c2y; uz_ = -s * c1z + cc * c2z;
  c1x = tx_; c1y = ty_; c1z = tz_; c2x = ux_; c2y = uy_; c2z = uz_;

  float f1x = wx - 0.08f * c1x + 0.02f * c2x;
  float f1y = wy - 0.08f * c1y + 0.02f * c2y;
  float f1z = wz - 0.08f * c1z + 0.02f * c2z;
  float f4x = wx - 0.08f * c1x - 0.02f * c2x;
  float f4y = wy - 0.08f * c1y - 0.02f * c2y;
  float f4z = wz - 0.08f * c1z - 0.02f * c2z;

  float dsx = shx - fox, dsy = shy - foy, dsz = shz - foz;
  float dwx = wx - fox, dwy = wy - foy, dwz = wz - foz;
  float bodyL = 0.5f * (sqrtf(dsx * dsx + dsy * dsy + dsz * dsz) +
                        sqrtf(dwx * dwx + dwy * dwy + dwz * dwz));
  float inv = fast_rcp(bodyL);

  float* o = out + ((size_t)b * NT + t) * 9;
  o[0] = (wx - shx) * inv; o[1] = (wy - shy) * inv; o[2] = (wz - shz) * inv;
  o[3] = (f1x - shx) * inv; o[4] = (f1y - shy) * inv; o[5] = (f1z - shz) * inv;
  o[6] = (f4x - shx) * inv; o[7] = (f4y - shy) * inv; o[8] = (f4z - shz) * inv;
}

// ---------------------------------------------------------------------------
extern "C" void kernel_launch(void* const* d_in, const int* in_sizes, int n_in,
                              void* d_out, int out_size, void* d_ws, size_t ws_size,
                              hipStream_t stream)
{
  fpp z     = (fpp)d_in[0];
  fpp W_fc  = (fpp)d_in[1];
  fpp b_fc  = (fpp)d_in[2];
  fpp bn_g  = (fpp)d_in[3];
  fpp bn_b  = (fpp)d_in[4];
  fpp Wih_f = (fpp)d_in[5];
  fpp Whh_f = (fpp)d_in[6];
  fpp bih_f = (fpp)d_in[7];
  fpp bhh_f = (fpp)d_in[8];
  fpp Wih_b = (fpp)d_in[9];
  fpp Whh_b = (fpp)d_in[10];
  fpp bih_b = (fpp)d_in[11];
  fpp bhh_b = (fpp)d_in[12];
  fpp aW1   = (fpp)d_in[13];
  fpp ab1   = (fpp)d_in[14];
  fpp aW2   = (fpp)d_in[15];
  fpp jW    = (fpp)d_in[16];
  fpp jb    = (fpp)d_in[17];

  float* ws     = (float*)d_ws;
  float* h0     = ws;                        // 2048*512 fp32
  float* xg_f   = h0 + 1048576;              // 2048*768 fp32
  float* xg_b   = xg_f + 1572864;            // 2048*768 fp32
  float* bns1   = xg_b + 1572864;            // 512
  float* bns2   = bns1 + 512;                // 512
  float* scores = bns2 + 512;                // 2048*60
  float* cbuf   = scores + 122880;           // 2048*512 (layout keep)
  __half* gseq    = (__half*)(cbuf + 1048576);   // 2048*60*512 fp16 (126 MB)
  __half* whh16_f = gseq + 62914560;             // 768*256
  __half* whh16_b = whh16_f + 196608;            // 768*256
  __half* w116    = whh16_b + 196608;            // 256*512
  __half* wih16_f = w116 + 131072;               // 768*512
  __half* wih16_b = wih16_f + 393216;            // 768*512
  __half* h16g    = wih16_b + 393216;            // 2048*512
  __half* jw16    = h16g + 1048576;              // 16*512
  float*  gJ      = (float*)(jw16 + 8192);       // 122880*16 fp32 (7.9 MB)

  // 0. weight conversions fp32->fp16 (pre-scaled log2 domain) + BN acc zero
  convert_w<<<5152, 256, 0, stream>>>(Whh_f, Whh_b, aW1, Wih_f, Wih_b, jW,
                                      whh16_f, whh16_b, w116, wih16_f, wih16_b,
                                      jw16);
  hipMemsetAsync(bns1, 0, 1024 * sizeof(float), stream);
  // 1. fc: h0 = z @ W_fc^T + b_fc (fp32, K=100)
  gemm_fc<<<dim3(32, 8), 256, 0, stream>>>(z, W_fc, b_fc, h0,
                                           NB, ND, NDL, NDL, NDL, ND);
  // 2. batchnorm (training stats, parallel partials) + leaky relu -> fp16 h
  bn_partial<<<64, 256, 0, stream>>>(h0, bns1, bns2);
  bn_lrelu_h16<<<4096, 256, 0, stream>>>(h0, bn_g, bn_b, bns1, bns2, h16g);
  // 3. BOTH time-invariant input projections in one launch
  gemm16_dual<<<dim3(32, 12, 2), 256, 0, stream>>>(
      h16g, wih16_f, wih16_b, bih_f, bih_b, xg_f, xg_b, NG, ND);
  // 4. ENTIRE GRU recurrence: one persistent launch, 8 waves/block
  gru_persistent<<<256, 512, 0, stream>>>(xg_f, xg_b, whh16_f, whh16_b,
                                          bhh_f, bhh_b, gseq);
  // 5. attention scores + gJ (2x4 wave partition, 512 thr, high occupancy)
  attn_score_mfma<<<960, 512, 0, stream>>>(gseq, w116, jw16, ab1, aW2,
                                           scores, gJ);
  // 6. fused softmax + cJ + FK
  attn_post<<<NB, 64, 0, stream>>>(scores, gJ, jb, (float*)d_out);
}